// Round 16
// baseline (361.122 us; speedup 1.0000x reference)
//
#include <hip/hip_runtime.h>
#include <stdint.h>

#define N_TOK 6144
#define DMODEL 768
#define NHEAD 3
#define DHEAD 256
#define NWORDS (N_TOK/32)  // 192 mask words per row
#define NT NWORDS          // 192 key tiles of 32 keys

typedef __bf16 bf16x8 __attribute__((ext_vector_type(8)));
typedef float f32x4 __attribute__((ext_vector_type(4)));
typedef unsigned short u16;
typedef u16 u16x8 __attribute__((ext_vector_type(8)));
typedef u16 u16x4 __attribute__((ext_vector_type(4)));
typedef unsigned int u32;

__device__ __forceinline__ u16 f2bf(float f) {
  __bf16 b = (__bf16)f;  // native RNE cvt on gfx950
  return __builtin_bit_cast(u16, b);
}
__device__ __forceinline__ float bf2f(u16 u) {
  union { u32 u; float f; } v; v.u = (u32)u << 16; return v.f;
}
__device__ __forceinline__ float lrelu(float v) { return v >= 0.f ? v : 0.2f * v; }

// ---------------- f32 -> bf16 bulk convert (8 elems/thread) ----------------
__global__ __launch_bounds__(256) void cvt_bf(const float* __restrict__ src,
                                              u16* __restrict__ dst) {
  size_t i = ((size_t)blockIdx.x * 256 + threadIdx.x) * 8;
  float4 a = *reinterpret_cast<const float4*>(src + i);
  float4 b = *reinterpret_cast<const float4*>(src + i + 4);
  u16x8 v = {f2bf(a.x), f2bf(a.y), f2bf(a.z), f2bf(a.w),
             f2bf(b.x), f2bf(b.y), f2bf(b.z), f2bf(b.w)};
  *reinterpret_cast<u16x8*>(dst + i) = v;
}

// ---------------- adj [N][N] int32 -> bitmask [N][NWORDS] ----------------
__global__ __launch_bounds__(256) void pack_adj(const int* __restrict__ adj,
                                                u32* __restrict__ bits) {
  size_t wid = (size_t)blockIdx.x * 256 + threadIdx.x;   // one 32-key word
  const int4* p = reinterpret_cast<const int4*>(adj + wid * 32);
  u32 m = 0;
#pragma unroll
  for (int i = 0; i < 8; ++i) {
    int4 v = p[i];
    m |= (v.x != 0 ? 1u : 0u) << (i * 4 + 0);
    m |= (v.y != 0 ? 1u : 0u) << (i * 4 + 1);
    m |= (v.z != 0 ? 1u : 0u) << (i * 4 + 2);
    m |= (v.w != 0 ? 1u : 0u) << (i * 4 + 3);
  }
  bits[wid] = m;
}

// ---------------- bf16 transpose: src[N][768] -> dst[768][N] ----------------
__global__ __launch_bounds__(256) void transpose_bf(const u16* __restrict__ src,
                                                    u16* __restrict__ dst) {
  __shared__ u16 t[64][72];
  const int n0 = blockIdx.x * 64, d0 = blockIdx.y * 64;
  const int tid = threadIdx.x;
#pragma unroll
  for (int i = 0; i < 2; ++i) {
    int c = tid + i * 256;
    int r = c >> 3, c8 = (c & 7) * 8;
    *reinterpret_cast<u16x8*>(&t[r][c8]) =
        *reinterpret_cast<const u16x8*>(src + (size_t)(n0 + r) * DMODEL + d0 + c8);
  }
  __syncthreads();
#pragma unroll
  for (int i = 0; i < 2; ++i) {
    int c = tid + i * 256;
    int dr = c >> 3, n8 = (c & 7) * 8;
    u16x8 v;
#pragma unroll
    for (int j = 0; j < 8; ++j) v[j] = t[n8 + j][dr];
    *reinterpret_cast<u16x8*>(dst + (size_t)(d0 + dr) * N_TOK + n0 + n8) = v;
  }
}

// ---------------- score bound precompute ----------------
__global__ void init_knmax(u32* knmax2) {
  if (threadIdx.x < NHEAD) knmax2[threadIdx.x] = 0;
}

__global__ __launch_bounds__(256) void knorm_max(const u16* __restrict__ xnew,
                                                 u32* __restrict__ knmax2) {
  int n = blockIdx.x * 256 + threadIdx.x;
  int h = blockIdx.y;
  const u16* row = xnew + (size_t)n * DMODEL + h * DHEAD;
  float s = 0.f;
#pragma unroll 4
  for (int i = 0; i < 32; ++i) {
    u16x8 v = *reinterpret_cast<const u16x8*>(row + i * 8);
#pragma unroll
    for (int j = 0; j < 8; ++j) { float f = bf2f(v[j]); s += f * f; }
  }
#pragma unroll
  for (int off = 1; off < 64; off <<= 1) s = fmaxf(s, __shfl_xor(s, off));
  if ((threadIdx.x & 63) == 0) atomicMax(knmax2 + h, __float_as_uint(s));
}

__global__ __launch_bounds__(256) void qbound(const u16* __restrict__ qbf,
                                              const u32* __restrict__ knmax2,
                                              float* __restrict__ Mrow) {
  int n = blockIdx.x * 256 + threadIdx.x;
  int h = blockIdx.y;
  const u16* row = qbf + (size_t)n * DMODEL + h * DHEAD;
  float s = 0.f;
#pragma unroll 4
  for (int i = 0; i < 32; ++i) {
    u16x8 v = *reinterpret_cast<const u16x8*>(row + i * 8);
#pragma unroll
    for (int j = 0; j < 8; ++j) { float f = bf2f(v[j]); s += f * f; }
  }
  float kn2 = __uint_as_float(knmax2[h]);
  Mrow[(size_t)h * N_TOK + n] = sqrtf(s * kn2);
}

// ---------------- NT GEMM (all-bf16 inputs): C = A @ W^T ----------------
// 128x128 tile + T3 2-phase reg staging (round-12 version, best measured).
template <int FINAL>
__global__ __launch_bounds__(256) void gemm_bf(const u16* __restrict__ A,
                                               const u16* __restrict__ W,
                                               const float* __restrict__ bias,
                                               const float* __restrict__ resid,
                                               u16* __restrict__ out_bf,
                                               float* __restrict__ out_f,
                                               float oscale) {
  __shared__ u16 As[128][72];
  __shared__ u16 Bs[128][72];
  const int tid = threadIdx.x;
  const int w = tid >> 6, lane = tid & 63, lr = lane & 15, lg = lane >> 4;
  const int m0 = blockIdx.x * 128, n0 = blockIdx.y * 128;
  const int wr = (w >> 1) * 64, wc = (w & 1) * 64;
  f32x4 acc[4][4] = {};
  u16x8 ast[4], bst[4];
  const int row = tid >> 3, c8 = (tid & 7) * 8;

  auto issue_tile = [&](int kt) {
#pragma unroll
    for (int i = 0; i < 4; ++i) {
      int r = row + i * 32;
      ast[i] = *reinterpret_cast<const u16x8*>(A + (size_t)(m0 + r) * DMODEL + kt * 64 + c8);
      bst[i] = *reinterpret_cast<const u16x8*>(W + (size_t)(n0 + r) * DMODEL + kt * 64 + c8);
    }
  };
  auto write_tile = [&]() {
#pragma unroll
    for (int i = 0; i < 4; ++i) {
      int r = row + i * 32;
      *reinterpret_cast<u16x8*>(&As[r][c8]) = ast[i];
      *reinterpret_cast<u16x8*>(&Bs[r][c8]) = bst[i];
    }
  };

  issue_tile(0);
  for (int kt = 0; kt < DMODEL / 64; ++kt) {
    __syncthreads();
    write_tile();
    if (kt + 1 < DMODEL / 64) issue_tile(kt + 1);
    __syncthreads();
#pragma unroll
    for (int ks = 0; ks < 2; ++ks) {
      bf16x8 a[4], b[4];
#pragma unroll
      for (int mi = 0; mi < 4; ++mi)
        a[mi] = *reinterpret_cast<const bf16x8*>(&As[wr + mi * 16 + lr][ks * 32 + lg * 8]);
#pragma unroll
      for (int ni = 0; ni < 4; ++ni)
        b[ni] = *reinterpret_cast<const bf16x8*>(&Bs[wc + ni * 16 + lr][ks * 32 + lg * 8]);
#pragma unroll
      for (int mi = 0; mi < 4; ++mi)
#pragma unroll
        for (int ni = 0; ni < 4; ++ni)
          acc[mi][ni] =
              __builtin_amdgcn_mfma_f32_16x16x32_bf16(a[mi], b[ni], acc[mi][ni], 0, 0, 0);
    }
  }
#pragma unroll
  for (int mi = 0; mi < 4; ++mi)
#pragma unroll
    for (int ni = 0; ni < 4; ++ni)
#pragma unroll
      for (int r = 0; r < 4; ++r) {
        int grow = m0 + wr + mi * 16 + lg * 4 + r;
        int gcol = n0 + wc + ni * 16 + lr;
        float v = lrelu(acc[mi][ni][r] + bias[gcol]);
        size_t idx = (size_t)grow * DMODEL + gcol;
        if (FINAL)
          out_f[idx] = resid[idx] + v;
        else
          out_bf[idx] = f2bf(v * oscale);
      }
}

// ---------------- fused masked flash attention (fixed-bound softmax, pair-PV) ----------------
// R12 inner structure and LDS layouts, but 512 threads = 8 WAVES per block:
// the K/V tile staging cost (fixed bytes per tile) is now amortized over 8
// waves instead of 4 -> per-wave LDS ops drop 44 -> 36/iter and staging regs
// halve (kst/vst = 32). Block = 128 q-rows; grid 48 x 3 x SPLIT.
template <int SPLIT>
__global__ __launch_bounds__(512) void attn_fused(
    const u16* __restrict__ Kmat,  // x_new bf16 [N][768]
    const u16* __restrict__ Qmat,  // q*0.1 bf16 [N][768]
    const u16* __restrict__ VT,    // x_new^T bf16 [768][N]
    const u32* __restrict__ bits,  // [N][NWORDS]
    const float* __restrict__ Mrow,// [H][N] score upper bounds
    const float* __restrict__ x,   // residual [N][768] f32 (SPLIT==1 only)
    u16* __restrict__ out2,        // bf16 [N][768] (SPLIT==1 only)
    float* __restrict__ Opart,     // [SPLIT][N][768] f32 partial O
    float* __restrict__ lpart) {   // [SPLIT][H][N] f32 partial l
  __shared__ u16 Ks[32][264];      // [key][dh]   (R12-proven layout)
  __shared__ u16 Vs[256][36];      // [dh][key]   (R12-proven layout)
  __shared__ u16 Ps[8][16][40];    // per-QK-wave [q][key]
  __shared__ float lss[128];       // per-q lsum (SPLIT==1 epilogue)
  const int tid = threadIdx.x;
  const int w = tid >> 6, lane = tid & 63, lr = lane & 15, lg = lane >> 4;
  const int q0 = blockIdx.x * 128;
  const int h = blockIdx.y;
  const int z = blockIdx.z;
  const int qrow = q0 + w * 16 + lr;
  const int qp = (w >> 1) * 2;     // PV pair base wave
  const int dbase = (w & 1) * 8;   // PV dh half (8 frags of 16)

  bf16x8 qf[8];
  {
    const u16* qrowp = Qmat + (size_t)qrow * DMODEL + h * DHEAD + lg * 8;
#pragma unroll
    for (int s = 0; s < 8; ++s) qf[s] = *reinterpret_cast<const bf16x8*>(qrowp + s * 32);
  }
  const float Mr = Mrow[(size_t)h * N_TOK + qrow];
  f32x4 o[2][8] = {};  // [pair q-subtile][dh frag]
  float lsum = 0.f;

  const int t0 = z * (NT / SPLIT), t1 = t0 + NT / SPLIT;

  u16x8 kst[2], vst[2];  // staging halved: 8 waves share the tile
  u32 wnext, wcur;

  auto issue_tile = [&](int kt) {
#pragma unroll
    for (int i = 0; i < 2; ++i) {
      int c = tid + i * 512;
      int kr = c >> 5, kc = (c & 31) * 8;
      kst[i] = *reinterpret_cast<const u16x8*>(
          Kmat + (size_t)(kt * 32 + kr) * DMODEL + h * DHEAD + kc);
      int vr = c >> 2, vc = (c & 3) * 8;
      vst[i] = *reinterpret_cast<const u16x8*>(
          VT + (size_t)(h * DHEAD + vr) * N_TOK + kt * 32 + vc);
    }
    wnext = bits[(size_t)qrow * NWORDS + kt];
  };
  auto write_tile = [&]() {
#pragma unroll
    for (int i = 0; i < 2; ++i) {
      int c = tid + i * 512;
      int kr = c >> 5, kc = (c & 31) * 8;
      *reinterpret_cast<u16x8*>(&Ks[kr][kc]) = kst[i];
      int vr = c >> 2, vc = (c & 3) * 8;
      *reinterpret_cast<u16x8*>(&Vs[vr][vc]) = vst[i];
    }
  };

  issue_tile(t0);

  for (int kt = t0; kt < t1; ++kt) {
    __syncthreads();
    write_tile();
    wcur = wnext;
    if (kt + 1 < t1) issue_tile(kt + 1);
    __syncthreads();

    f32x4 st[2] = {};
#pragma unroll
    for (int s = 0; s < 8; ++s) {
      bf16x8 k0 = *reinterpret_cast<const bf16x8*>(&Ks[lr][s * 32 + lg * 8]);
      bf16x8 k1 = *reinterpret_cast<const bf16x8*>(&Ks[16 + lr][s * 32 + lg * 8]);
      st[0] = __builtin_amdgcn_mfma_f32_16x16x32_bf16(k0, qf[s], st[0], 0, 0, 0);
      st[1] = __builtin_amdgcn_mfma_f32_16x16x32_bf16(k1, qf[s], st[1], 0, 0, 0);
    }
#pragma unroll
    for (int kb = 0; kb < 2; ++kb) {
      u16x4 pk;
#pragma unroll
      for (int r = 0; r < 4; ++r) {
        int keyl = kb * 16 + lg * 4 + r;
        float pe = ((wcur >> keyl) & 1u) ? __expf(st[kb][r] - Mr) : 0.f;
        lsum += pe;
        pk[r] = f2bf(pe);
      }
      *reinterpret_cast<u16x4*>(&Ps[w][lr][kb * 16 + lg * 4]) = pk;
    }
    __syncthreads();   // Ps visible across the wave pair

    bf16x8 pf0 = *reinterpret_cast<const bf16x8*>(&Ps[qp][lr][lg * 8]);
    bf16x8 pf1 = *reinterpret_cast<const bf16x8*>(&Ps[qp + 1][lr][lg * 8]);
#pragma unroll
    for (int d = 0; d < 8; ++d) {
      bf16x8 vf = *reinterpret_cast<const bf16x8*>(&Vs[(dbase + d) * 16 + lr][lg * 8]);
      o[0][d] = __builtin_amdgcn_mfma_f32_16x16x32_bf16(pf0, vf, o[0][d], 0, 0, 0);
      o[1][d] = __builtin_amdgcn_mfma_f32_16x16x32_bf16(pf1, vf, o[1][d], 0, 0, 0);
    }
  }

  lsum += __shfl_xor(lsum, 16);
  lsum += __shfl_xor(lsum, 32);

  if (SPLIT == 1) {
    if (lane < 16) lss[w * 16 + lr] = lsum;
    __syncthreads();
#pragma unroll
    for (int t = 0; t < 2; ++t)
#pragma unroll
      for (int d = 0; d < 8; ++d)
#pragma unroll
        for (int r = 0; r < 4; ++r) {
          int grow = q0 + (w >> 1) * 32 + t * 16 + lg * 4 + r;
          int gcol = h * DHEAD + (w & 1) * 128 + d * 16 + lr;
          size_t idx = (size_t)grow * DMODEL + gcol;
          float ls = lss[(w >> 1) * 32 + t * 16 + lg * 4 + r];
          out2[idx] = f2bf(x[idx] + o[t][d][r] / ls);
        }
  } else {
    float* Op = Opart + (size_t)z * N_TOK * DMODEL;
#pragma unroll
    for (int t = 0; t < 2; ++t)
#pragma unroll
      for (int d = 0; d < 8; ++d)
#pragma unroll
        for (int r = 0; r < 4; ++r) {
          int grow = q0 + (w >> 1) * 32 + t * 16 + lg * 4 + r;
          int gcol = h * DHEAD + (w & 1) * 128 + d * 16 + lr;
          Op[(size_t)grow * DMODEL + gcol] = o[t][d][r];
        }
    if (lane < 16)
      lpart[((size_t)z * NHEAD + h) * N_TOK + qrow] = lsum;
  }
}

// ---------------- combine SPLIT key-split partials: out2 = bf16(x + ΣO/Σl) ----------------
template <int SPLIT>
__global__ __launch_bounds__(256) void attn_combine(const float* __restrict__ Opart,
                                                    const float* __restrict__ lpart,
                                                    const float* __restrict__ x,
                                                    u16* __restrict__ out2) {
  int g = blockIdx.x * 256 + threadIdx.x;  // one float4 group
  int q = g / (DMODEL / 4);
  int col = (g % (DMODEL / 4)) * 4;
  int h = col >> 8;
  float L = 0.f;
#pragma unroll
  for (int s = 0; s < SPLIT; ++s)
    L += lpart[((size_t)s * NHEAD + h) * N_TOK + q];
  float rL = 1.f / L;
  size_t idx = (size_t)q * DMODEL + col;
  float4 acc = make_float4(0.f, 0.f, 0.f, 0.f);
#pragma unroll
  for (int s = 0; s < SPLIT; ++s) {
    float4 O = *reinterpret_cast<const float4*>(Opart + (size_t)s * N_TOK * DMODEL + idx);
    acc.x += O.x; acc.y += O.y; acc.z += O.z; acc.w += O.w;
  }
  float4 xv = *reinterpret_cast<const float4*>(x + idx);
  u16x4 r;
  r[0] = f2bf(xv.x + acc.x * rL);
  r[1] = f2bf(xv.y + acc.y * rL);
  r[2] = f2bf(xv.z + acc.z * rL);
  r[3] = f2bf(xv.w + acc.w * rL);
  *reinterpret_cast<u16x4*>(out2 + idx) = r;
}

extern "C" void kernel_launch(void* const* d_in, const int* in_sizes, int n_in,
                              void* d_out, int out_size, void* d_ws, size_t ws_size,
                              hipStream_t stream) {
  const float* x     = (const float*)d_in[0];
  const int*   adj   = (const int*)d_in[1];
  const float* W_fc  = (const float*)d_in[2];
  const float* b_fc  = (const float*)d_in[3];
  const float* W_qfc = (const float*)d_in[4];
  const float* b_qfc = (const float*)d_in[5];
  const float* W_fin = (const float*)d_in[6];
  const float* b_fin = (const float*)d_in[7];
  float* out = (float*)d_out;

  char* ws = (char*)d_ws;
  size_t off = 0;
  auto alloc = [&](size_t bytes) {
    char* p = ws + off;
    off += (bytes + 255) & ~(size_t)255;
    return p;
  };
  u16* xnew_bf = (u16*)alloc((size_t)N_TOK * DMODEL * 2);
  u16* q_bf    = (u16*)alloc((size_t)N_TOK * DMODEL * 2);
  u16* xT      = (u16*)alloc((size_t)DMODEL * N_TOK * 2);
  u16* out2_bf = (u16*)alloc((size_t)N_TOK * DMODEL * 2);
  u16* x_bf    = (u16*)alloc((size_t)N_TOK * DMODEL * 2);
  u16* wfc_bf  = (u16*)alloc((size_t)DMODEL * DMODEL * 2);
  u16* wqf_bf  = (u16*)alloc((size_t)DMODEL * DMODEL * 2);
  u16* wfi_bf  = (u16*)alloc((size_t)DMODEL * DMODEL * 2);
  u32* bits    = (u32*)alloc((size_t)N_TOK * NWORDS * 4);
  u32* knmax2  = (u32*)alloc(NHEAD * 4);
  float* Mrow  = (float*)alloc((size_t)NHEAD * N_TOK * 4);
  size_t base_off = off;
  float* Opart = (float*)alloc((size_t)6 * N_TOK * DMODEL * 4);
  float* lpart = (float*)alloc((size_t)6 * NHEAD * N_TOK * 4);
  size_t need6 = off;
  auto needN = [&](size_t n) {
    return base_off + (((size_t)n * N_TOK * DMODEL * 4 + 255) & ~(size_t)255) +
           (((size_t)n * NHEAD * N_TOK * 4 + 255) & ~(size_t)255);
  };
  const int split = (ws_size >= need6) ? 6
                  : (ws_size >= needN(4)) ? 4
                  : (ws_size >= needN(2)) ? 2 : 1;

  cvt_bf<<<N_TOK * DMODEL / 8 / 256, 256, 0, stream>>>(x, x_bf);
  cvt_bf<<<DMODEL * DMODEL / 8 / 256, 256, 0, stream>>>(W_fc, wfc_bf);
  cvt_bf<<<DMODEL * DMODEL / 8 / 256, 256, 0, stream>>>(W_qfc, wqf_bf);
  cvt_bf<<<DMODEL * DMODEL / 8 / 256, 256, 0, stream>>>(W_fin, wfi_bf);
  pack_adj<<<N_TOK * NWORDS / 256, 256, 0, stream>>>(adj, bits);

  dim3 ggrid(N_TOK / 128, DMODEL / 128);
  gemm_bf<0><<<ggrid, 256, 0, stream>>>(x_bf, wfc_bf, b_fc, nullptr, xnew_bf, nullptr, 1.0f);
  gemm_bf<0><<<ggrid, 256, 0, stream>>>(xnew_bf, wqf_bf, b_qfc, nullptr, q_bf, nullptr,
                                        0.1f);  // fold score scale into q
  transpose_bf<<<dim3(N_TOK / 64, DMODEL / 64), 256, 0, stream>>>(xnew_bf, xT);
  init_knmax<<<1, 64, 0, stream>>>(knmax2);
  dim3 bgrid(N_TOK / 256, NHEAD);
  knorm_max<<<bgrid, 256, 0, stream>>>(xnew_bf, knmax2);
  qbound<<<bgrid, 256, 0, stream>>>(q_bf, knmax2, Mrow);
  dim3 cgrid(N_TOK * DMODEL / 4 / 256);
  if (split == 6) {
    attn_fused<6><<<dim3(N_TOK / 128, NHEAD, 6), 512, 0, stream>>>(
        xnew_bf, q_bf, xT, bits, Mrow, x, out2_bf, Opart, lpart);
    attn_combine<6><<<cgrid, 256, 0, stream>>>(Opart, lpart, x, out2_bf);
  } else if (split == 4) {
    attn_fused<4><<<dim3(N_TOK / 128, NHEAD, 4), 512, 0, stream>>>(
        xnew_bf, q_bf, xT, bits, Mrow, x, out2_bf, Opart, lpart);
    attn_combine<4><<<cgrid, 256, 0, stream>>>(Opart, lpart, x, out2_bf);
  } else if (split == 2) {
    attn_fused<2><<<dim3(N_TOK / 128, NHEAD, 2), 512, 0, stream>>>(
        xnew_bf, q_bf, xT, bits, Mrow, x, out2_bf, Opart, lpart);
    attn_combine<2><<<cgrid, 256, 0, stream>>>(Opart, lpart, x, out2_bf);
  } else {
    attn_fused<1><<<dim3(N_TOK / 128, NHEAD, 1), 512, 0, stream>>>(
        xnew_bf, q_bf, xT, bits, Mrow, x, out2_bf, Opart, lpart);
  }
  gemm_bf<1><<<ggrid, 256, 0, stream>>>(out2_bf, wfi_bf, b_fin, x, nullptr, out, 1.0f);
}

// Round 17
// 339.684 us; speedup vs baseline: 1.0631x; 1.0631x over previous
//
#include <hip/hip_runtime.h>
#include <stdint.h>

#define N_TOK 6144
#define DMODEL 768
#define NHEAD 3
#define DHEAD 256
#define NWORDS (N_TOK/32)  // 192 mask words per row
#define NT64 (N_TOK/64)    // 96 key tiles of 64 keys

typedef __bf16 bf16x8 __attribute__((ext_vector_type(8)));
typedef float f32x4 __attribute__((ext_vector_type(4)));
typedef float f32x16 __attribute__((ext_vector_type(16)));
typedef unsigned short u16;
typedef u16 u16x8 __attribute__((ext_vector_type(8)));
typedef u16 u16x4 __attribute__((ext_vector_type(4)));
typedef unsigned int u32;

__device__ __forceinline__ u16 f2bf(float f) {
  __bf16 b = (__bf16)f;  // native RNE cvt on gfx950
  return __builtin_bit_cast(u16, b);
}
__device__ __forceinline__ float bf2f(u16 u) {
  union { u32 u; float f; } v; v.u = (u32)u << 16; return v.f;
}
__device__ __forceinline__ float lrelu(float v) { return v >= 0.f ? v : 0.2f * v; }

// ---------------- f32 -> bf16 bulk convert (8 elems/thread) ----------------
__global__ __launch_bounds__(256) void cvt_bf(const float* __restrict__ src,
                                              u16* __restrict__ dst) {
  size_t i = ((size_t)blockIdx.x * 256 + threadIdx.x) * 8;
  float4 a = *reinterpret_cast<const float4*>(src + i);
  float4 b = *reinterpret_cast<const float4*>(src + i + 4);
  u16x8 v = {f2bf(a.x), f2bf(a.y), f2bf(a.z), f2bf(a.w),
             f2bf(b.x), f2bf(b.y), f2bf(b.z), f2bf(b.w)};
  *reinterpret_cast<u16x8*>(dst + i) = v;
}

// ---------------- adj [N][N] int32 -> bitmask [N][NWORDS] ----------------
__global__ __launch_bounds__(256) void pack_adj(const int* __restrict__ adj,
                                                u32* __restrict__ bits) {
  size_t wid = (size_t)blockIdx.x * 256 + threadIdx.x;   // one 32-key word
  const int4* p = reinterpret_cast<const int4*>(adj + wid * 32);
  u32 m = 0;
#pragma unroll
  for (int i = 0; i < 8; ++i) {
    int4 v = p[i];
    m |= (v.x != 0 ? 1u : 0u) << (i * 4 + 0);
    m |= (v.y != 0 ? 1u : 0u) << (i * 4 + 1);
    m |= (v.z != 0 ? 1u : 0u) << (i * 4 + 2);
    m |= (v.w != 0 ? 1u : 0u) << (i * 4 + 3);
  }
  bits[wid] = m;
}

// ---------------- bf16 transpose: src[N][768] -> dst[768][N] ----------------
__global__ __launch_bounds__(256) void transpose_bf(const u16* __restrict__ src,
                                                    u16* __restrict__ dst) {
  __shared__ u16 t[64][72];
  const int n0 = blockIdx.x * 64, d0 = blockIdx.y * 64;
  const int tid = threadIdx.x;
#pragma unroll
  for (int i = 0; i < 2; ++i) {
    int c = tid + i * 256;
    int r = c >> 3, c8 = (c & 7) * 8;
    *reinterpret_cast<u16x8*>(&t[r][c8]) =
        *reinterpret_cast<const u16x8*>(src + (size_t)(n0 + r) * DMODEL + d0 + c8);
  }
  __syncthreads();
#pragma unroll
  for (int i = 0; i < 2; ++i) {
    int c = tid + i * 256;
    int dr = c >> 3, n8 = (c & 7) * 8;
    u16x8 v;
#pragma unroll
    for (int j = 0; j < 8; ++j) v[j] = t[n8 + j][dr];
    *reinterpret_cast<u16x8*>(dst + (size_t)(d0 + dr) * N_TOK + n0 + n8) = v;
  }
}

// ---------------- score bound precompute ----------------
__global__ void init_knmax(u32* knmax2) {
  if (threadIdx.x < NHEAD) knmax2[threadIdx.x] = 0;
}

__global__ __launch_bounds__(256) void knorm_max(const u16* __restrict__ xnew,
                                                 u32* __restrict__ knmax2) {
  int n = blockIdx.x * 256 + threadIdx.x;
  int h = blockIdx.y;
  const u16* row = xnew + (size_t)n * DMODEL + h * DHEAD;
  float s = 0.f;
#pragma unroll 4
  for (int i = 0; i < 32; ++i) {
    u16x8 v = *reinterpret_cast<const u16x8*>(row + i * 8);
#pragma unroll
    for (int j = 0; j < 8; ++j) { float f = bf2f(v[j]); s += f * f; }
  }
#pragma unroll
  for (int off = 1; off < 64; off <<= 1) s = fmaxf(s, __shfl_xor(s, off));
  if ((threadIdx.x & 63) == 0) atomicMax(knmax2 + h, __float_as_uint(s));
}

__global__ __launch_bounds__(256) void qbound(const u16* __restrict__ qbf,
                                              const u32* __restrict__ knmax2,
                                              float* __restrict__ Mrow) {
  int n = blockIdx.x * 256 + threadIdx.x;
  int h = blockIdx.y;
  const u16* row = qbf + (size_t)n * DMODEL + h * DHEAD;
  float s = 0.f;
#pragma unroll 4
  for (int i = 0; i < 32; ++i) {
    u16x8 v = *reinterpret_cast<const u16x8*>(row + i * 8);
#pragma unroll
    for (int j = 0; j < 8; ++j) { float f = bf2f(v[j]); s += f * f; }
  }
  float kn2 = __uint_as_float(knmax2[h]);
  Mrow[(size_t)h * N_TOK + n] = sqrtf(s * kn2);
}

// ---------------- NT GEMM (all-bf16 inputs): C = A @ W^T ----------------
// 128x128 tile + T3 2-phase reg staging (round-12 version, best measured).
template <int FINAL>
__global__ __launch_bounds__(256) void gemm_bf(const u16* __restrict__ A,
                                               const u16* __restrict__ W,
                                               const float* __restrict__ bias,
                                               const float* __restrict__ resid,
                                               u16* __restrict__ out_bf,
                                               float* __restrict__ out_f,
                                               float oscale) {
  __shared__ u16 As[128][72];
  __shared__ u16 Bs[128][72];
  const int tid = threadIdx.x;
  const int w = tid >> 6, lane = tid & 63, lr = lane & 15, lg = lane >> 4;
  const int m0 = blockIdx.x * 128, n0 = blockIdx.y * 128;
  const int wr = (w >> 1) * 64, wc = (w & 1) * 64;
  f32x4 acc[4][4] = {};
  u16x8 ast[4], bst[4];
  const int row = tid >> 3, c8 = (tid & 7) * 8;

  auto issue_tile = [&](int kt) {
#pragma unroll
    for (int i = 0; i < 4; ++i) {
      int r = row + i * 32;
      ast[i] = *reinterpret_cast<const u16x8*>(A + (size_t)(m0 + r) * DMODEL + kt * 64 + c8);
      bst[i] = *reinterpret_cast<const u16x8*>(W + (size_t)(n0 + r) * DMODEL + kt * 64 + c8);
    }
  };
  auto write_tile = [&]() {
#pragma unroll
    for (int i = 0; i < 4; ++i) {
      int r = row + i * 32;
      *reinterpret_cast<u16x8*>(&As[r][c8]) = ast[i];
      *reinterpret_cast<u16x8*>(&Bs[r][c8]) = bst[i];
    }
  };

  issue_tile(0);
  for (int kt = 0; kt < DMODEL / 64; ++kt) {
    __syncthreads();
    write_tile();
    if (kt + 1 < DMODEL / 64) issue_tile(kt + 1);
    __syncthreads();
#pragma unroll
    for (int ks = 0; ks < 2; ++ks) {
      bf16x8 a[4], b[4];
#pragma unroll
      for (int mi = 0; mi < 4; ++mi)
        a[mi] = *reinterpret_cast<const bf16x8*>(&As[wr + mi * 16 + lr][ks * 32 + lg * 8]);
#pragma unroll
      for (int ni = 0; ni < 4; ++ni)
        b[ni] = *reinterpret_cast<const bf16x8*>(&Bs[wc + ni * 16 + lr][ks * 32 + lg * 8]);
#pragma unroll
      for (int mi = 0; mi < 4; ++mi)
#pragma unroll
        for (int ni = 0; ni < 4; ++ni)
          acc[mi][ni] =
              __builtin_amdgcn_mfma_f32_16x16x32_bf16(a[mi], b[ni], acc[mi][ni], 0, 0, 0);
    }
  }
#pragma unroll
  for (int mi = 0; mi < 4; ++mi)
#pragma unroll
    for (int ni = 0; ni < 4; ++ni)
#pragma unroll
      for (int r = 0; r < 4; ++r) {
        int grow = m0 + wr + mi * 16 + lg * 4 + r;
        int gcol = n0 + wc + ni * 16 + lr;
        float v = lrelu(acc[mi][ni][r] + bias[gcol]);
        size_t idx = (size_t)grow * DMODEL + gcol;
        if (FINAL)
          out_f[idx] = resid[idx] + v;
        else
          out_bf[idx] = f2bf(v * oscale);
      }
}

// ---------------- fused masked flash attention: 32x32 QK + 16x16 pair-PV ----------------
// 512 thr = 8 waves = 4 q-groups (32 q each) x 2 key-halves. KVBLK=64.
// QK^T: wave (g,kh) computes S^T[32k of half kh][32q of group g] with 16
// mfma_32x32x16 (2x FLOP per LDS fragment read vs 16x16). Q in 64 VGPRs.
// Fixed-bound softmax (p = exp(s-M)); P staged to LDS; PV uses the R12-proven
// 16x16 machinery: pair {2g,2g+1} splits dh, each wave 32q x 128dh, o = 64 AGPR.
// All LDS rows padded to 16B multiples so b128 ops stay single-op.
template <int SPLIT>
__global__ __launch_bounds__(512) void attn_fused(
    const u16* __restrict__ Kmat,  // x_new bf16 [N][768]
    const u16* __restrict__ Qmat,  // q*0.1 bf16 [N][768]
    const u16* __restrict__ VT,    // x_new^T bf16 [768][N]
    const u32* __restrict__ bits,  // [N][NWORDS]
    const float* __restrict__ Mrow,// [H][N] score upper bounds
    const float* __restrict__ x,   // residual [N][768] f32 (SPLIT==1 only)
    u16* __restrict__ out2,        // bf16 [N][768] (SPLIT==1 only)
    float* __restrict__ Opart,     // [SPLIT][N][768] f32 partial O
    float* __restrict__ lpart) {   // [SPLIT][H][N] f32 partial l
  __shared__ u16 Ks[64][264];      // [key][dh]   row 528B (16B-mult)
  __shared__ u16 Vs[256][72];      // [dh][key]   row 144B (16B-mult)
  __shared__ u16 Ps[4][32][72];    // [group][q][key] row 144B
  __shared__ float lss[2][128];    // per-half per-q lsum
  const int tid = threadIdx.x;
  const int w = tid >> 6, lane = tid & 63;
  const int g = w >> 1, kh = w & 1;
  const int ll = lane & 31, hi = lane >> 5;      // 32x32 operand coords
  const int lr = lane & 15, lg = lane >> 4;      // 16x16 operand coords
  const int q0 = blockIdx.x * 128;
  const int h = blockIdx.y;
  const int z = blockIdx.z;
  const int qrow = q0 + g * 32 + ll;             // this lane's q (QK phase)
  const int dhb = kh * 8;                        // PV dh half: 8 frags of 16

  // Q fragments: B-operand of 32x32x16. qf[s] = Q[qrow][s*16 + hi*8 .. +8]
  bf16x8 qf[16];
  {
    const u16* qp = Qmat + (size_t)qrow * DMODEL + h * DHEAD + hi * 8;
#pragma unroll
    for (int s = 0; s < 16; ++s) qf[s] = *reinterpret_cast<const bf16x8*>(qp + s * 16);
  }
  const float Mr = Mrow[(size_t)h * N_TOK + qrow];
  f32x4 o[2][8] = {};  // [q-subtile of group][dh frag]
  float lsum = 0.f;

  const int t0 = z * (NT64 / SPLIT), t1 = t0 + NT64 / SPLIT;

  u16x8 kst[4], vst[4];
  u32 wnext, wcur;

  auto issue_tile = [&](int kt) {
#pragma unroll
    for (int i = 0; i < 4; ++i) {
      int c = tid + i * 512;
      int kr = c >> 5, kc = (c & 31) * 8;  // K tile 64x256
      kst[i] = *reinterpret_cast<const u16x8*>(
          Kmat + (size_t)(kt * 64 + kr) * DMODEL + h * DHEAD + kc);
      int vr = c >> 3, vc = (c & 7) * 8;   // V^T tile 256x64
      vst[i] = *reinterpret_cast<const u16x8*>(
          VT + (size_t)(h * DHEAD + vr) * N_TOK + kt * 64 + vc);
    }
    wnext = bits[(size_t)qrow * NWORDS + kt * 2 + kh];
  };
  auto write_tile = [&]() {
#pragma unroll
    for (int i = 0; i < 4; ++i) {
      int c = tid + i * 512;
      int kr = c >> 5, kc = (c & 31) * 8;
      *reinterpret_cast<u16x8*>(&Ks[kr][kc]) = kst[i];
      int vr = c >> 3, vc = (c & 7) * 8;
      *reinterpret_cast<u16x8*>(&Vs[vr][vc]) = vst[i];
    }
  };

  issue_tile(t0);

  for (int kt = t0; kt < t1; ++kt) {
    __syncthreads();   // (A) prev-iter PV reads of Ks/Vs/Ps complete
    write_tile();
    wcur = wnext;
    if (kt + 1 < t1) issue_tile(kt + 1);
    __syncthreads();   // (B) K/V tile visible

    // S^T[32k half kh][32q group g], K-dim 256 in 16 steps of 16.
    f32x16 st = {};
#pragma unroll
    for (int s = 0; s < 16; ++s) {
      bf16x8 kf = *reinterpret_cast<const bf16x8*>(&Ks[kh * 32 + ll][s * 16 + hi * 8]);
      st = __builtin_amdgcn_mfma_f32_32x32x16_bf16(kf, qf[s], st, 0, 0, 0);
    }
    // p = exp(s - M) gated by adjacency bit; C/D row = (r&3)+8*(r>>2)+4*hi.
#pragma unroll
    for (int rg = 0; rg < 4; ++rg) {
      u16x4 pk;
#pragma unroll
      for (int j = 0; j < 4; ++j) {
        int keyl = rg * 8 + 4 * hi + j;   // key within this 32-half
        float pe = ((wcur >> keyl) & 1u) ? __expf(st[rg * 4 + j] - Mr) : 0.f;
        lsum += pe;
        pk[j] = f2bf(pe);
      }
      *reinterpret_cast<u16x4*>(&Ps[g][ll][kh * 32 + rg * 8 + hi * 4]) = pk;
    }
    __syncthreads();   // (C) full P (both halves) visible to the pair

    // PV (R12 16x16 pair machinery): this wave: group g's 32q x 128dh(kh half)
#pragma unroll
    for (int ks = 0; ks < 2; ++ks) {
      bf16x8 pf0 = *reinterpret_cast<const bf16x8*>(&Ps[g][lr][ks * 32 + lg * 8]);
      bf16x8 pf1 = *reinterpret_cast<const bf16x8*>(&Ps[g][16 + lr][ks * 32 + lg * 8]);
#pragma unroll
      for (int d = 0; d < 8; ++d) {
        bf16x8 vf = *reinterpret_cast<const bf16x8*>(
            &Vs[(dhb + d) * 16 + lr][ks * 32 + lg * 8]);
        o[0][d] = __builtin_amdgcn_mfma_f32_16x16x32_bf16(pf0, vf, o[0][d], 0, 0, 0);
        o[1][d] = __builtin_amdgcn_mfma_f32_16x16x32_bf16(pf1, vf, o[1][d], 0, 0, 0);
      }
    }
  }

  // lsum: lane's q = g*32+ll, partial over key-half kh. Fold hi, then halves.
  lsum += __shfl_xor(lsum, 32);
  if (lane < 32) lss[kh][g * 32 + lane] = lsum;
  __syncthreads();

  if (SPLIT == 1) {
#pragma unroll
    for (int t = 0; t < 2; ++t)
#pragma unroll
      for (int d = 0; d < 8; ++d)
#pragma unroll
        for (int r = 0; r < 4; ++r) {
          int gq = g * 32 + t * 16 + lg * 4 + r;
          float ls = lss[0][gq] + lss[1][gq];
          int grow = q0 + gq;
          int gcol = h * DHEAD + kh * 128 + d * 16 + lr;
          size_t idx = (size_t)grow * DMODEL + gcol;
          out2[idx] = f2bf(x[idx] + o[t][d][r] / ls);
        }
  } else {
    float* Op = Opart + (size_t)z * N_TOK * DMODEL;
#pragma unroll
    for (int t = 0; t < 2; ++t)
#pragma unroll
      for (int d = 0; d < 8; ++d)
#pragma unroll
        for (int r = 0; r < 4; ++r) {
          int grow = q0 + g * 32 + t * 16 + lg * 4 + r;
          int gcol = h * DHEAD + kh * 128 + d * 16 + lr;
          Op[(size_t)grow * DMODEL + gcol] = o[t][d][r];
        }
    if (kh == 0 && lane < 32) {
      int gq = g * 32 + lane;
      lpart[((size_t)z * NHEAD + h) * N_TOK + q0 + gq] = lss[0][gq] + lss[1][gq];
    }
  }
}

// ---------------- combine SPLIT key-split partials: out2 = bf16(x + ΣO/Σl) ----------------
template <int SPLIT>
__global__ __launch_bounds__(256) void attn_combine(const float* __restrict__ Opart,
                                                    const float* __restrict__ lpart,
                                                    const float* __restrict__ x,
                                                    u16* __restrict__ out2) {
  int g = blockIdx.x * 256 + threadIdx.x;  // one float4 group
  int q = g / (DMODEL / 4);
  int col = (g % (DMODEL / 4)) * 4;
  int h = col >> 8;
  float L = 0.f;
#pragma unroll
  for (int s = 0; s < SPLIT; ++s)
    L += lpart[((size_t)s * NHEAD + h) * N_TOK + q];
  float rL = 1.f / L;
  size_t idx = (size_t)q * DMODEL + col;
  float4 acc = make_float4(0.f, 0.f, 0.f, 0.f);
#pragma unroll
  for (int s = 0; s < SPLIT; ++s) {
    float4 O = *reinterpret_cast<const float4*>(Opart + (size_t)s * N_TOK * DMODEL + idx);
    acc.x += O.x; acc.y += O.y; acc.z += O.z; acc.w += O.w;
  }
  float4 xv = *reinterpret_cast<const float4*>(x + idx);
  u16x4 r;
  r[0] = f2bf(xv.x + acc.x * rL);
  r[1] = f2bf(xv.y + acc.y * rL);
  r[2] = f2bf(xv.z + acc.z * rL);
  r[3] = f2bf(xv.w + acc.w * rL);
  *reinterpret_cast<u16x4*>(out2 + idx) = r;
}

extern "C" void kernel_launch(void* const* d_in, const int* in_sizes, int n_in,
                              void* d_out, int out_size, void* d_ws, size_t ws_size,
                              hipStream_t stream) {
  const float* x     = (const float*)d_in[0];
  const int*   adj   = (const int*)d_in[1];
  const float* W_fc  = (const float*)d_in[2];
  const float* b_fc  = (const float*)d_in[3];
  const float* W_qfc = (const float*)d_in[4];
  const float* b_qfc = (const float*)d_in[5];
  const float* W_fin = (const float*)d_in[6];
  const float* b_fin = (const float*)d_in[7];
  float* out = (float*)d_out;

  char* ws = (char*)d_ws;
  size_t off = 0;
  auto alloc = [&](size_t bytes) {
    char* p = ws + off;
    off += (bytes + 255) & ~(size_t)255;
    return p;
  };
  u16* xnew_bf = (u16*)alloc((size_t)N_TOK * DMODEL * 2);
  u16* q_bf    = (u16*)alloc((size_t)N_TOK * DMODEL * 2);
  u16* xT      = (u16*)alloc((size_t)DMODEL * N_TOK * 2);
  u16* out2_bf = (u16*)alloc((size_t)N_TOK * DMODEL * 2);
  u16* x_bf    = (u16*)alloc((size_t)N_TOK * DMODEL * 2);
  u16* wfc_bf  = (u16*)alloc((size_t)DMODEL * DMODEL * 2);
  u16* wqf_bf  = (u16*)alloc((size_t)DMODEL * DMODEL * 2);
  u16* wfi_bf  = (u16*)alloc((size_t)DMODEL * DMODEL * 2);
  u32* bits    = (u32*)alloc((size_t)N_TOK * NWORDS * 4);
  u32* knmax2  = (u32*)alloc(NHEAD * 4);
  float* Mrow  = (float*)alloc((size_t)NHEAD * N_TOK * 4);
  size_t base_off = off;
  float* Opart = (float*)alloc((size_t)6 * N_TOK * DMODEL * 4);
  float* lpart = (float*)alloc((size_t)6 * NHEAD * N_TOK * 4);
  size_t need6 = off;
  auto needN = [&](size_t n) {
    return base_off + (((size_t)n * N_TOK * DMODEL * 4 + 255) & ~(size_t)255) +
           (((size_t)n * NHEAD * N_TOK * 4 + 255) & ~(size_t)255);
  };
  const int split = (ws_size >= need6) ? 6
                  : (ws_size >= needN(4)) ? 4
                  : (ws_size >= needN(2)) ? 2 : 1;

  cvt_bf<<<N_TOK * DMODEL / 8 / 256, 256, 0, stream>>>(x, x_bf);
  cvt_bf<<<DMODEL * DMODEL / 8 / 256, 256, 0, stream>>>(W_fc, wfc_bf);
  cvt_bf<<<DMODEL * DMODEL / 8 / 256, 256, 0, stream>>>(W_qfc, wqf_bf);
  cvt_bf<<<DMODEL * DMODEL / 8 / 256, 256, 0, stream>>>(W_fin, wfi_bf);
  pack_adj<<<N_TOK * NWORDS / 256, 256, 0, stream>>>(adj, bits);

  dim3 ggrid(N_TOK / 128, DMODEL / 128);
  gemm_bf<0><<<ggrid, 256, 0, stream>>>(x_bf, wfc_bf, b_fc, nullptr, xnew_bf, nullptr, 1.0f);
  gemm_bf<0><<<ggrid, 256, 0, stream>>>(xnew_bf, wqf_bf, b_qfc, nullptr, q_bf, nullptr,
                                        0.1f);  // fold score scale into q
  transpose_bf<<<dim3(N_TOK / 64, DMODEL / 64), 256, 0, stream>>>(xnew_bf, xT);
  init_knmax<<<1, 64, 0, stream>>>(knmax2);
  dim3 bgrid(N_TOK / 256, NHEAD);
  knorm_max<<<bgrid, 256, 0, stream>>>(xnew_bf, knmax2);
  qbound<<<bgrid, 256, 0, stream>>>(q_bf, knmax2, Mrow);
  dim3 cgrid(N_TOK * DMODEL / 4 / 256);
  if (split == 6) {
    attn_fused<6><<<dim3(N_TOK / 128, NHEAD, 6), 512, 0, stream>>>(
        xnew_bf, q_bf, xT, bits, Mrow, x, out2_bf, Opart, lpart);
    attn_combine<6><<<cgrid, 256, 0, stream>>>(Opart, lpart, x, out2_bf);
  } else if (split == 4) {
    attn_fused<4><<<dim3(N_TOK / 128, NHEAD, 4), 512, 0, stream>>>(
        xnew_bf, q_bf, xT, bits, Mrow, x, out2_bf, Opart, lpart);
    attn_combine<4><<<cgrid, 256, 0, stream>>>(Opart, lpart, x, out2_bf);
  } else if (split == 2) {
    attn_fused<2><<<dim3(N_TOK / 128, NHEAD, 2), 512, 0, stream>>>(
        xnew_bf, q_bf, xT, bits, Mrow, x, out2_bf, Opart, lpart);
    attn_combine<2><<<cgrid, 256, 0, stream>>>(Opart, lpart, x, out2_bf);
  } else {
    attn_fused<1><<<dim3(N_TOK / 128, NHEAD, 1), 512, 0, stream>>>(
        xnew_bf, q_bf, xT, bits, Mrow, x, out2_bf, Opart, lpart);
  }
  gemm_bf<1><<<ggrid, 256, 0, stream>>>(out2_bf, wfi_bf, b_fin, x, nullptr, out, 1.0f);
}